// Round 12
// baseline (23854.065 us; speedup 1.0000x reference)
//
#include <hip/hip_runtime.h>

constexpr int N_ = 4096;
constexpr int D_ = 64;
constexpr int O_ = 64;
constexpr int T_ = 4096;
constexpr float LEAK_ = 0.8f;
constexpr int NBLK = 256;        // 1 block/CU, full machine; all co-resident
constexpr int NTHR = 1024;       // 16 waves
constexpr int NWAVE = 16;
constexpr int RPB = N_ / NBLK;   // 16 rows per block, ONE row per wave
constexpr int KELL = 512;        // ELL slots/row (max nnz ~485, 5-sigma margin)
constexpr int GRP = KELL / 64;   // 8 gather groups
constexpr int PDEPTH = 8;        // y-partials ring depth
constexpr int BPW = NBLK / NWAVE; // 16 blocks whose rows each wave stages

typedef unsigned long long u64;
#define LD64(p)   __hip_atomic_load((const u64*)(p), __ATOMIC_RELAXED, __HIP_MEMORY_SCOPE_AGENT)
#define ST64(p,v) __hip_atomic_store((u64*)(p), (v), __ATOMIC_RELAXED, __HIP_MEMORY_SCOPE_AGENT)
#define LD32(p)   __hip_atomic_load((const unsigned*)(p), __ATOMIC_RELAXED, __HIP_MEMORY_SCOPE_AGENT)
#define ST32(p,v) __hip_atomic_store((unsigned*)(p), (v), __ATOMIC_RELAXED, __HIP_MEMORY_SCOPE_AGENT)

__device__ __forceinline__ u64 mkpair(float x, unsigned seq) {
    return ((u64)seq << 32) | (u64)__float_as_uint(x);
}
__device__ __forceinline__ unsigned pseq(u64 v) { return (unsigned)(v >> 32); }
__device__ __forceinline__ float pval(u64 v) { return __uint_as_float((unsigned)v); }

// Prep A: transpose W_out weight part -> WoT[row][o], extract bias col bo.
__global__ void esn_prep(const float* __restrict__ W_out,
                         float* __restrict__ WoT, float* __restrict__ bo) {
    int idx = blockIdx.x * blockDim.x + threadIdx.x;
    if (idx < N_ * O_) {
        int row = idx / O_;
        int o = idx - row * O_;
        WoT[idx] = W_out[o * (N_ + 1) + row];
    }
    if (idx < O_) bo[idx] = W_out[idx * (N_ + 1) + N_];
}

// Prep B: dense W -> ELL with BANK-BALANCED slot assignment (bank = col & 31
// round-robined across the 8 slot-groups -> ~2-3-way conflicts, mostly free).
__global__ __launch_bounds__(64) void esn_sparsify(
    const float* __restrict__ W,
    unsigned short* __restrict__ cols, float* __restrict__ vals) {
    const int row = blockIdx.x;
    const int lane = threadIdx.x;
    __shared__ unsigned short nnz_c[KELL];
    __shared__ float nnz_w[KELL];
    __shared__ short slot_nnz[KELL];
    for (int s = lane; s < KELL; s += 64) slot_nnz[s] = -1;

    const float* Wr = W + (size_t)row * N_;
    const unsigned long long ltmask = (1ull << lane) - 1ull;
    int cnt = 0;
    for (int c0 = 0; c0 < N_; c0 += 64) {
        float w = Wr[c0 + lane];
        unsigned long long m = __ballot(w != 0.0f);
        if (w != 0.0f) {
            int pos = cnt + __popcll(m & ltmask);
            if (pos < KELL) { nnz_c[pos] = (unsigned short)(c0 + lane); nnz_w[pos] = w; }
        }
        cnt += __popcll(m);
    }
    if (cnt > KELL) cnt = KELL;
    __syncthreads();

    if (lane == 0) {
        unsigned char fill[GRP];
        unsigned char nxt[32];
        for (int g = 0; g < GRP; ++g) fill[g] = 0;
        for (int bnk = 0; bnk < 32; ++bnk) nxt[bnk] = 0;
        for (int i = 0; i < cnt; ++i) {
            int bnk = nnz_c[i] & 31;
            int g = nxt[bnk];
            int tries = 0;
            while (fill[g] >= 64 && tries < GRP) { g = (g + 1) % GRP; ++tries; }
            slot_nnz[g * 64 + fill[g]] = (short)i;
            fill[g]++;
            nxt[bnk] = (unsigned char)((g + 1) % GRP);
        }
    }
    __syncthreads();

    unsigned short* crow = cols + (size_t)row * KELL;
    float* vrow = vals + (size_t)row * KELL;
    for (int s = lane; s < KELL; s += 64) {
        int i = slot_nnz[s];
        crow[s] = (i >= 0) ? nnz_c[i] : 0;
        vrow[s] = (i >= 0) ? nnz_w[i] : 0.0f;
    }
}

__global__ __launch_bounds__(NTHR) void esn_main(
    const float* __restrict__ inputs,
    const unsigned short* __restrict__ cols, const float* __restrict__ vals,
    const float* __restrict__ W_in, const float* __restrict__ b,
    const float* __restrict__ WoT, const float* __restrict__ bo,
    float* __restrict__ y, u64* __restrict__ xpairs, u64* __restrict__ ppairs,
    unsigned* __restrict__ sent)
{
    __shared__ float x_lds[2][N_];          // 32 KB, double-buffered
    __shared__ float u_lds[2][D_];
    __shared__ float pw_lds[2][NWAVE][O_];  // 8 KB, double-buffered
    const int tid = threadIdx.x;
    const int bid = blockIdx.x;
    const int wave = tid >> 6;
    const int lane = tid & 63;
    const int row = bid * RPB + wave;       // this wave's row, for ALL steps

    // Hoist row-constant weights into registers (zero weight traffic in loop).
    unsigned short cc[GRP];
    float vv[GRP];
    #pragma unroll
    for (int j = 0; j < GRP; ++j) {
        cc[j] = cols[(size_t)row * KELL + 64 * j + lane];
        vv[j] = vals[(size_t)row * KELL + 64 * j + lane];
    }
    const float win  = W_in[row * D_ + lane];
    const float brow = b[row];
    const float wo   = WoT[row * O_ + lane];

    // Preamble: x(-1) = 0, u(0) staged.
    #pragma unroll
    for (int k = 0; k < 4; ++k) x_lds[0][tid + k * NTHR] = 0.f;
    if (tid < D_) u_lds[0][tid] = inputs[tid];
    __syncthreads();

    float xo = 0.f;   // x_{t-1}[row], carried in-register (leak term)

    for (int t = 0; t < T_; ++t) {
        const int pt = t & 1;

        // Sparse gather from LDS + input fold + butterfly reduce.
        float acc = 0.f;
        #pragma unroll
        for (int j = 0; j < GRP; ++j) acc += vv[j] * x_lds[pt][cc[j]];
        acc += win * u_lds[pt][lane];
        #pragma unroll
        for (int off = 32; off; off >>= 1) acc += __shfl_xor(acc, off);
        float xn = (1.f - LEAK_) * xo + LEAK_ * tanhf(acc + brow);
        xo = xn;

        // Publish self-validating {xn, seq=t+1} pair immediately.
        if (lane == 0)
            ST64(&xpairs[(size_t)pt * N_ + row], mkpair(xn, (unsigned)(t + 1)));
        pw_lds[pt][wave][lane] = wo * xn;

        // u(t+1) prefetch: wave 3 issues the load now (stall absorbed by its
        // poll below), writes u_lds after staging — off the sentinel path.
        float uv_pf = 0.f;
        if (wave == 3 && t + 1 < T_) uv_pf = inputs[(t + 1) * D_ + lane];

        __syncthreads();   // sync #1: all 16 pair-stores of this block issued

        // Sentinel hint: block arrived (data pairs self-validate on load).
        if (tid == 0) ST32(&sent[bid], (unsigned)(t + 1));

        // Poll ONLY the 16 sentinels of the blocks whose rows this wave
        // stages (lanes 0-15; 64 B per round — no fabric congestion).
        {
            const unsigned tgt = (unsigned)(t + 1);
            while (__ballot(lane < BPW &&
                            LD32(&sent[wave * BPW + lane]) < tgt) != 0ull) {}
        }

        // Bulk-load those 256 rows once (coalesced), verify embedded seqs.
        {
            const u64* xp = xpairs + (size_t)pt * N_ + wave * (BPW * RPB);
            const unsigned tgt = (unsigned)(t + 1);
            u64 v[4];
            #pragma unroll
            for (int k = 0; k < 4; ++k) v[k] = LD64(&xp[k * 64 + lane]);
            while (true) {
                int stale = 0;
                #pragma unroll
                for (int k = 0; k < 4; ++k)
                    if (pseq(v[k]) != tgt) { v[k] = LD64(&xp[k * 64 + lane]); stale = 1; }
                if (__ballot(stale) == 0ull) break;
            }
            #pragma unroll
            for (int k = 0; k < 4; ++k)
                x_lds[pt ^ 1][wave * (BPW * RPB) + k * 64 + lane] = pval(v[k]);
        }
        if (wave == 3 && t + 1 < T_) u_lds[pt ^ 1][lane] = uv_pf;
        __syncthreads();   // sync #2: next-step x and u staged

        // Post-sync aux (deadline = next sync #2; off the publish->poll path).
        if (wave == 1) {
            // Block partial of y(t): sum 16 per-wave rows, publish with seq.
            float s = 0.f;
            #pragma unroll
            for (int w = 0; w < NWAVE; ++w) s += pw_lds[pt][w][lane];
            ST64(&ppairs[(size_t)(t & (PDEPTH - 1)) * (NBLK * O_) + bid * O_ + lane],
                 mkpair(s, (unsigned)(t + 1)));
        } else if (wave == 2 && t >= 2 && bid < O_) {
            // y(t-2): gather 256 block-partials for output o = bid.
            const u64* pp = ppairs + (size_t)((t - 2) & (PDEPTH - 1)) * (NBLK * O_);
            const unsigned tgt = (unsigned)(t - 1);
            u64 v0 = LD64(&pp[lane * O_ + bid]);
            u64 v1 = LD64(&pp[(lane + 64) * O_ + bid]);
            u64 v2 = LD64(&pp[(lane + 128) * O_ + bid]);
            u64 v3 = LD64(&pp[(lane + 192) * O_ + bid]);
            while (true) {
                int stale = 0;
                if (pseq(v0) != tgt) { v0 = LD64(&pp[lane * O_ + bid]); stale = 1; }
                if (pseq(v1) != tgt) { v1 = LD64(&pp[(lane + 64) * O_ + bid]); stale = 1; }
                if (pseq(v2) != tgt) { v2 = LD64(&pp[(lane + 128) * O_ + bid]); stale = 1; }
                if (pseq(v3) != tgt) { v3 = LD64(&pp[(lane + 192) * O_ + bid]); stale = 1; }
                if (__ballot(stale) == 0ull) break;
            }
            float s = pval(v0) + pval(v1) + pval(v2) + pval(v3);
            #pragma unroll
            for (int off = 32; off; off >>= 1) s += __shfl_xor(s, off);
            if (lane == 0) y[(t - 2) * O_ + bid] = s + bo[bid];
        }
    }

    // ---- Drain: y(T-2), y(T-1) (partial(T-1) published by wave 1 at t=T-1).
    if (wave == 2 && bid < O_) {
        for (int tt = T_ - 2; tt < T_; ++tt) {
            const u64* pp = ppairs + (size_t)(tt & (PDEPTH - 1)) * (NBLK * O_);
            const unsigned tgt = (unsigned)(tt + 1);
            u64 v0 = LD64(&pp[lane * O_ + bid]);
            u64 v1 = LD64(&pp[(lane + 64) * O_ + bid]);
            u64 v2 = LD64(&pp[(lane + 128) * O_ + bid]);
            u64 v3 = LD64(&pp[(lane + 192) * O_ + bid]);
            while (true) {
                int stale = 0;
                if (pseq(v0) != tgt) { v0 = LD64(&pp[lane * O_ + bid]); stale = 1; }
                if (pseq(v1) != tgt) { v1 = LD64(&pp[(lane + 64) * O_ + bid]); stale = 1; }
                if (pseq(v2) != tgt) { v2 = LD64(&pp[(lane + 128) * O_ + bid]); stale = 1; }
                if (pseq(v3) != tgt) { v3 = LD64(&pp[(lane + 192) * O_ + bid]); stale = 1; }
                if (__ballot(stale) == 0ull) break;
            }
            float s = pval(v0) + pval(v1) + pval(v2) + pval(v3);
            #pragma unroll
            for (int off = 32; off; off >>= 1) s += __shfl_xor(s, off);
            if (lane == 0) y[tt * O_ + bid] = s + bo[bid];
        }
    }
}

extern "C" void kernel_launch(void* const* d_in, const int* in_sizes, int n_in,
                              void* d_out, int out_size, void* d_ws, size_t ws_size,
                              hipStream_t stream) {
    const float* inputs = (const float*)d_in[0];
    const float* W      = (const float*)d_in[1];
    const float* W_in   = (const float*)d_in[2];
    const float* b      = (const float*)d_in[3];
    const float* W_out  = (const float*)d_in[4];
    float* y  = (float*)d_out;

    // Workspace:
    //   xpairs: 2 * N u64         (64 KB)   {x, seq} pairs, ping-pong
    //   ppairs: PDEPTH*NBLK*O u64 (1 MB)    {partial, seq} ring
    //   sent:   NBLK u32 (pad 4 KB)          per-block arrival sentinels
    //   floats: WoT[N*O] | bo[O] | vals[N*KELL] ; then u16 cols[N*KELL]
    u64* xpairs = (u64*)d_ws;
    u64* ppairs = xpairs + 2 * N_;
    unsigned* sent = (unsigned*)(ppairs + (size_t)PDEPTH * NBLK * O_);
    float* WoT  = (float*)((char*)sent + 4096);
    float* bo   = WoT + N_ * O_;
    float* vals = bo + O_;
    unsigned short* cols = (unsigned short*)(vals + (size_t)N_ * KELL);

    // Zero all seq/sentinel words every call -> replay-deterministic.
    size_t seq_bytes = (2 * N_ + (size_t)PDEPTH * NBLK * O_) * sizeof(u64) + 4096;
    hipMemsetAsync(d_ws, 0, seq_bytes, stream);

    hipLaunchKernelGGL(esn_prep, dim3((N_ * O_ + 255) / 256), dim3(256),
                       0, stream, W_out, WoT, bo);
    hipLaunchKernelGGL(esn_sparsify, dim3(N_), dim3(64),
                       0, stream, W, cols, vals);

    hipLaunchKernelGGL(esn_main, dim3(NBLK), dim3(NTHR), 0, stream,
                       inputs, cols, vals, W_in, b, WoT, bo, y,
                       xpairs, ppairs, sent);
}

// Round 13
// 21935.832 us; speedup vs baseline: 1.0874x; 1.0874x over previous
//
#include <hip/hip_runtime.h>

constexpr int N_ = 4096;
constexpr int D_ = 64;
constexpr int O_ = 64;
constexpr int T_ = 4096;
constexpr float LEAK_ = 0.8f;
constexpr int NBLK = 256;        // 1 block/CU, full machine; all co-resident
constexpr int NTHR = 1024;       // 16 waves
constexpr int NWAVE = 16;
constexpr int RPB = N_ / NBLK;   // 16 rows per block, ONE row per wave
constexpr int KELL = 512;        // ELL slots/row (max nnz ~485, 5-sigma margin)
constexpr int GRP = KELL / 64;   // 8 gather groups
constexpr int PDEPTH = 8;        // y-partials ring depth
constexpr int PWAVES = 8;        // waves 0..7 poll x
constexpr int XSPT = N_ / (PWAVES * 64);  // 8 x-slots per polling thread

typedef unsigned long long u64;
#define LD64(p)   __hip_atomic_load((const u64*)(p), __ATOMIC_RELAXED, __HIP_MEMORY_SCOPE_AGENT)
#define ST64(p,v) __hip_atomic_store((u64*)(p), (v), __ATOMIC_RELAXED, __HIP_MEMORY_SCOPE_AGENT)

__device__ __forceinline__ u64 mkpair(float x, unsigned seq) {
    return ((u64)seq << 32) | (u64)__float_as_uint(x);
}
__device__ __forceinline__ unsigned pseq(u64 v) { return (unsigned)(v >> 32); }
__device__ __forceinline__ float pval(u64 v) { return __uint_as_float((unsigned)v); }

// Prep A: transpose W_out weight part -> WoT[row][o], extract bias col bo.
__global__ void esn_prep(const float* __restrict__ W_out,
                         float* __restrict__ WoT, float* __restrict__ bo) {
    int idx = blockIdx.x * blockDim.x + threadIdx.x;
    if (idx < N_ * O_) {
        int row = idx / O_;
        int o = idx - row * O_;
        WoT[idx] = W_out[o * (N_ + 1) + row];
    }
    if (idx < O_) bo[idx] = W_out[idx * (N_ + 1) + N_];
}

// Prep B: dense W -> ELL with BANK-BALANCED slot assignment (bank = col & 31
// round-robined across the 8 slot-groups -> ~2-3-way conflicts, mostly free).
__global__ __launch_bounds__(64) void esn_sparsify(
    const float* __restrict__ W,
    unsigned short* __restrict__ cols, float* __restrict__ vals) {
    const int row = blockIdx.x;
    const int lane = threadIdx.x;
    __shared__ unsigned short nnz_c[KELL];
    __shared__ float nnz_w[KELL];
    __shared__ short slot_nnz[KELL];
    for (int s = lane; s < KELL; s += 64) slot_nnz[s] = -1;

    const float* Wr = W + (size_t)row * N_;
    const unsigned long long ltmask = (1ull << lane) - 1ull;
    int cnt = 0;
    for (int c0 = 0; c0 < N_; c0 += 64) {
        float w = Wr[c0 + lane];
        unsigned long long m = __ballot(w != 0.0f);
        if (w != 0.0f) {
            int pos = cnt + __popcll(m & ltmask);
            if (pos < KELL) { nnz_c[pos] = (unsigned short)(c0 + lane); nnz_w[pos] = w; }
        }
        cnt += __popcll(m);
    }
    if (cnt > KELL) cnt = KELL;
    __syncthreads();

    if (lane == 0) {
        unsigned char fill[GRP];
        unsigned char nxt[32];
        for (int g = 0; g < GRP; ++g) fill[g] = 0;
        for (int bnk = 0; bnk < 32; ++bnk) nxt[bnk] = 0;
        for (int i = 0; i < cnt; ++i) {
            int bnk = nnz_c[i] & 31;
            int g = nxt[bnk];
            int tries = 0;
            while (fill[g] >= 64 && tries < GRP) { g = (g + 1) % GRP; ++tries; }
            slot_nnz[g * 64 + fill[g]] = (short)i;
            fill[g]++;
            nxt[bnk] = (unsigned char)((g + 1) % GRP);
        }
    }
    __syncthreads();

    unsigned short* crow = cols + (size_t)row * KELL;
    float* vrow = vals + (size_t)row * KELL;
    for (int s = lane; s < KELL; s += 64) {
        int i = slot_nnz[s];
        crow[s] = (i >= 0) ? nnz_c[i] : 0;
        vrow[s] = (i >= 0) ? nnz_w[i] : 0.0f;
    }
}

__global__ __launch_bounds__(NTHR) void esn_main(
    const float* __restrict__ inputs,
    const unsigned short* __restrict__ cols, const float* __restrict__ vals,
    const float* __restrict__ W_in, const float* __restrict__ b,
    const float* __restrict__ WoT, const float* __restrict__ bo,
    float* __restrict__ y, u64* __restrict__ xpairs, u64* __restrict__ ppairs)
{
    __shared__ float x_lds[2][N_];          // 32 KB, double-buffered
    __shared__ float u_lds[2][D_];
    __shared__ float pw_lds[2][NWAVE][O_];  // 8 KB, double-buffered
    const int tid = threadIdx.x;
    const int bid = blockIdx.x;
    const int wave = tid >> 6;
    const int lane = tid & 63;
    const int row = bid * RPB + wave;       // this wave's row, for ALL steps

    // Hoist row-constant weights into registers (zero weight traffic in loop).
    unsigned short cc[GRP];
    float vv[GRP];
    #pragma unroll
    for (int j = 0; j < GRP; ++j) {
        cc[j] = cols[(size_t)row * KELL + 64 * j + lane];
        vv[j] = vals[(size_t)row * KELL + 64 * j + lane];
    }
    const float win  = W_in[row * D_ + lane];
    const float brow = b[row];
    const float wo   = WoT[row * O_ + lane];

    // Preamble: x(-1) = 0, u(0) staged.
    #pragma unroll
    for (int k = 0; k < 4; ++k) x_lds[0][tid + k * NTHR] = 0.f;
    if (tid < D_) u_lds[0][tid] = inputs[tid];
    __syncthreads();

    float xo = 0.f;   // x_{t-1}[row], carried in-register (leak term)

    for (int t = 0; t < T_; ++t) {
        const int pt = t & 1;

        // Sparse gather from LDS + input fold + butterfly reduce.
        float acc = 0.f;
        #pragma unroll
        for (int j = 0; j < GRP; ++j) acc += vv[j] * x_lds[pt][cc[j]];
        acc += win * u_lds[pt][lane];
        #pragma unroll
        for (int off = 32; off; off >>= 1) acc += __shfl_xor(acc, off);
        float xn = (1.f - LEAK_) * xo + LEAK_ * tanhf(acc + brow);
        xo = xn;

        // Publish {xn, seq=t+1} immediately — nothing else precedes it.
        if (lane == 0)
            ST64(&xpairs[(size_t)pt * N_ + row], mkpair(xn, (unsigned)(t + 1)));
        pw_lds[pt][wave][lane] = wo * xn;

        if (wave < PWAVES) {
            // Poll x(t): 8 slots/thread, all loads in flight; PROGRESSIVE
            // staging — each slot goes to LDS the moment its seq validates,
            // per-thread exit (no wave-wide ballot on the hot path).
            const u64* xp = xpairs + (size_t)pt * N_;
            const unsigned tgt = (unsigned)(t + 1);
            u64 v[XSPT];
            #pragma unroll
            for (int k = 0; k < XSPT; ++k) v[k] = LD64(&xp[tid + k * 512]);
            unsigned pend = (1u << XSPT) - 1u;
            while (pend) {
                #pragma unroll
                for (int k = 0; k < XSPT; ++k) {
                    if (pend & (1u << k)) {
                        if (pseq(v[k]) == tgt) {
                            x_lds[pt ^ 1][tid + k * 512] = pval(v[k]);
                            pend &= ~(1u << k);
                        } else {
                            v[k] = LD64(&xp[tid + k * 512]);
                        }
                    }
                }
            }
        } else if (wave == 8) {
            // Publish block partial of y(t-1) from the PREVIOUS parity buffer
            // (written before last sync -> visible, not yet overwritten).
            if (t >= 1) {
                float s = 0.f;
                #pragma unroll
                for (int w = 0; w < NWAVE; ++w) s += pw_lds[pt ^ 1][w][lane];
                ST64(&ppairs[(size_t)((t - 1) & (PDEPTH - 1)) * (NBLK * O_) + bid * O_ + lane],
                     mkpair(s, (unsigned)t));
            }
        } else if (wave == 9) {
            // y(t-3): partials published 2 iterations ago -> fresh in steady
            // state; poll loop is just a safety net.
            if (t >= 3 && bid < O_) {
                const int tt = t - 3;
                const u64* pp = ppairs + (size_t)(tt & (PDEPTH - 1)) * (NBLK * O_);
                const unsigned tgt = (unsigned)(tt + 1);
                u64 v0 = LD64(&pp[lane * O_ + bid]);
                u64 v1 = LD64(&pp[(lane + 64) * O_ + bid]);
                u64 v2 = LD64(&pp[(lane + 128) * O_ + bid]);
                u64 v3 = LD64(&pp[(lane + 192) * O_ + bid]);
                while (true) {
                    int stale = 0;
                    if (pseq(v0) != tgt) { v0 = LD64(&pp[lane * O_ + bid]); stale = 1; }
                    if (pseq(v1) != tgt) { v1 = LD64(&pp[(lane + 64) * O_ + bid]); stale = 1; }
                    if (pseq(v2) != tgt) { v2 = LD64(&pp[(lane + 128) * O_ + bid]); stale = 1; }
                    if (pseq(v3) != tgt) { v3 = LD64(&pp[(lane + 192) * O_ + bid]); stale = 1; }
                    if (__ballot(stale) == 0ull) break;
                }
                float s = pval(v0) + pval(v1) + pval(v2) + pval(v3);
                #pragma unroll
                for (int off = 32; off; off >>= 1) s += __shfl_xor(s, off);
                if (lane == 0) y[tt * O_ + bid] = s + bo[bid];
            }
        } else if (wave == 10) {
            if (t + 1 < T_ && lane < D_) u_lds[pt ^ 1][lane] = inputs[(t + 1) * D_ + lane];
        }
        __syncthreads();   // the ONLY sync per step
    }

    // ---- Drain ----
    // Publish y-partials of step T-1 (pw_lds[(T-1)&1] visible after last sync).
    if (wave == 8) {
        float s = 0.f;
        #pragma unroll
        for (int w = 0; w < NWAVE; ++w) s += pw_lds[(T_ - 1) & 1][w][lane];
        ST64(&ppairs[(size_t)((T_ - 1) & (PDEPTH - 1)) * (NBLK * O_) + bid * O_ + lane],
             mkpair(s, (unsigned)T_));
    }
    // Reduce y(T-3), y(T-2), y(T-1).
    if (wave == 9 && bid < O_) {
        for (int tt = T_ - 3; tt < T_; ++tt) {
            const u64* pp = ppairs + (size_t)(tt & (PDEPTH - 1)) * (NBLK * O_);
            const unsigned tgt = (unsigned)(tt + 1);
            u64 v0 = LD64(&pp[lane * O_ + bid]);
            u64 v1 = LD64(&pp[(lane + 64) * O_ + bid]);
            u64 v2 = LD64(&pp[(lane + 128) * O_ + bid]);
            u64 v3 = LD64(&pp[(lane + 192) * O_ + bid]);
            while (true) {
                int stale = 0;
                if (pseq(v0) != tgt) { v0 = LD64(&pp[lane * O_ + bid]); stale = 1; }
                if (pseq(v1) != tgt) { v1 = LD64(&pp[(lane + 64) * O_ + bid]); stale = 1; }
                if (pseq(v2) != tgt) { v2 = LD64(&pp[(lane + 128) * O_ + bid]); stale = 1; }
                if (pseq(v3) != tgt) { v3 = LD64(&pp[(lane + 192) * O_ + bid]); stale = 1; }
                if (__ballot(stale) == 0ull) break;
            }
            float s = pval(v0) + pval(v1) + pval(v2) + pval(v3);
            #pragma unroll
            for (int off = 32; off; off >>= 1) s += __shfl_xor(s, off);
            if (lane == 0) y[tt * O_ + bid] = s + bo[bid];
        }
    }
}

extern "C" void kernel_launch(void* const* d_in, const int* in_sizes, int n_in,
                              void* d_out, int out_size, void* d_ws, size_t ws_size,
                              hipStream_t stream) {
    const float* inputs = (const float*)d_in[0];
    const float* W      = (const float*)d_in[1];
    const float* W_in   = (const float*)d_in[2];
    const float* b      = (const float*)d_in[3];
    const float* W_out  = (const float*)d_in[4];
    float* y  = (float*)d_out;

    // Workspace:
    //   xpairs: 2 * N u64         (64 KB)   {x, seq} pairs, ping-pong
    //   ppairs: PDEPTH*NBLK*O u64 (1 MB)    {partial, seq} ring
    //   floats: WoT[N*O] | bo[O] | vals[N*KELL] ; then u16 cols[N*KELL]
    u64* xpairs = (u64*)d_ws;
    u64* ppairs = xpairs + 2 * N_;
    float* WoT  = (float*)(ppairs + (size_t)PDEPTH * NBLK * O_);
    float* bo   = WoT + N_ * O_;
    float* vals = bo + O_;
    unsigned short* cols = (unsigned short*)(vals + (size_t)N_ * KELL);

    // Zero all seq words (xpairs + ppairs) every call -> replay-deterministic.
    size_t seq_bytes = (2 * N_ + (size_t)PDEPTH * NBLK * O_) * sizeof(u64);
    hipMemsetAsync(d_ws, 0, seq_bytes, stream);

    hipLaunchKernelGGL(esn_prep, dim3((N_ * O_ + 255) / 256), dim3(256),
                       0, stream, W_out, WoT, bo);
    hipLaunchKernelGGL(esn_sparsify, dim3(N_), dim3(64),
                       0, stream, W, cols, vals);

    hipLaunchKernelGGL(esn_main, dim3(NBLK), dim3(NTHR), 0, stream,
                       inputs, cols, vals, W_in, b, WoT, bo, y,
                       xpairs, ppairs);
}

// Round 14
// 13763.951 us; speedup vs baseline: 1.7331x; 1.5937x over previous
//
#include <hip/hip_runtime.h>

constexpr int N_ = 4096;
constexpr int D_ = 64;
constexpr int O_ = 64;
constexpr int T_ = 4096;
constexpr float LEAK_ = 0.8f;
constexpr int NBLK = 256;        // 1 block/CU, full machine; all co-resident
constexpr int NTHR = 1024;       // 16 waves
constexpr int NWAVE = 16;
constexpr int RPB = N_ / NBLK;   // 16 rows per block, ONE row per wave
constexpr int KELL = 512;        // ELL slots/row (max nnz ~485, 5-sigma margin)
constexpr int GRP = KELL / 64;   // 8 gather groups
constexpr int PDEPTH = 8;        // y-partials ring depth (skew-proof)
constexpr int SPT = N_ / NTHR;   // 4 x-slots per thread

typedef unsigned long long u64;
#define LD64(p)   __hip_atomic_load((const u64*)(p), __ATOMIC_RELAXED, __HIP_MEMORY_SCOPE_AGENT)
#define ST64(p,v) __hip_atomic_store((u64*)(p), (v), __ATOMIC_RELAXED, __HIP_MEMORY_SCOPE_AGENT)

__device__ __forceinline__ u64 mkpair(float x, unsigned seq) {
    return ((u64)seq << 32) | (u64)__float_as_uint(x);
}
__device__ __forceinline__ unsigned pseq(u64 v) { return (unsigned)(v >> 32); }
__device__ __forceinline__ float pval(u64 v) { return __uint_as_float((unsigned)v); }

// Prep A: transpose W_out weight part -> WoT[row][o], extract bias col bo.
__global__ void esn_prep(const float* __restrict__ W_out,
                         float* __restrict__ WoT, float* __restrict__ bo) {
    int idx = blockIdx.x * blockDim.x + threadIdx.x;
    if (idx < N_ * O_) {
        int row = idx / O_;
        int o = idx - row * O_;
        WoT[idx] = W_out[o * (N_ + 1) + row];
    }
    if (idx < O_) bo[idx] = W_out[idx * (N_ + 1) + N_];
}

// Prep B: dense W -> ELL with BANK-BALANCED slot assignment (bank = col & 31
// round-robined across the 8 slot-groups -> ~2-3-way conflicts, mostly free).
__global__ __launch_bounds__(64) void esn_sparsify(
    const float* __restrict__ W,
    unsigned short* __restrict__ cols, float* __restrict__ vals) {
    const int row = blockIdx.x;
    const int lane = threadIdx.x;
    __shared__ unsigned short nnz_c[KELL];
    __shared__ float nnz_w[KELL];
    __shared__ short slot_nnz[KELL];
    for (int s = lane; s < KELL; s += 64) slot_nnz[s] = -1;

    const float* Wr = W + (size_t)row * N_;
    const unsigned long long ltmask = (1ull << lane) - 1ull;
    int cnt = 0;
    for (int c0 = 0; c0 < N_; c0 += 64) {
        float w = Wr[c0 + lane];
        unsigned long long m = __ballot(w != 0.0f);
        if (w != 0.0f) {
            int pos = cnt + __popcll(m & ltmask);
            if (pos < KELL) { nnz_c[pos] = (unsigned short)(c0 + lane); nnz_w[pos] = w; }
        }
        cnt += __popcll(m);
    }
    if (cnt > KELL) cnt = KELL;
    __syncthreads();

    if (lane == 0) {
        unsigned char fill[GRP];
        unsigned char nxt[32];
        for (int g = 0; g < GRP; ++g) fill[g] = 0;
        for (int bnk = 0; bnk < 32; ++bnk) nxt[bnk] = 0;
        for (int i = 0; i < cnt; ++i) {
            int bnk = nnz_c[i] & 31;
            int g = nxt[bnk];
            int tries = 0;
            while (fill[g] >= 64 && tries < GRP) { g = (g + 1) % GRP; ++tries; }
            slot_nnz[g * 64 + fill[g]] = (short)i;
            fill[g]++;
            nxt[bnk] = (unsigned char)((g + 1) % GRP);
        }
    }
    __syncthreads();

    unsigned short* crow = cols + (size_t)row * KELL;
    float* vrow = vals + (size_t)row * KELL;
    for (int s = lane; s < KELL; s += 64) {
        int i = slot_nnz[s];
        crow[s] = (i >= 0) ? nnz_c[i] : 0;
        vrow[s] = (i >= 0) ? nnz_w[i] : 0.0f;
    }
}

__global__ __launch_bounds__(NTHR) void esn_main(
    const float* __restrict__ inputs,
    const unsigned short* __restrict__ cols, const float* __restrict__ vals,
    const float* __restrict__ W_in, const float* __restrict__ b,
    const float* __restrict__ WoT, const float* __restrict__ bo,
    float* __restrict__ y, u64* __restrict__ xpairs, u64* __restrict__ ppairs)
{
    __shared__ float x_lds[2][N_];          // 32 KB, double-buffered
    __shared__ float u_lds[2][D_];
    __shared__ float pw_lds[2][NWAVE][O_];  // 8 KB
    const int tid = threadIdx.x;
    const int bid = blockIdx.x;
    const int wave = tid >> 6;
    const int lane = tid & 63;
    const int row = bid * RPB + wave;       // this wave's row, for ALL 4096 steps

    // Hoist row-constant weights into registers (zero weight traffic in loop).
    unsigned short cc[GRP];
    float vv[GRP];
    #pragma unroll
    for (int j = 0; j < GRP; ++j) {
        cc[j] = cols[(size_t)row * KELL + 64 * j + lane];
        vv[j] = vals[(size_t)row * KELL + 64 * j + lane];
    }
    const float win  = W_in[row * D_ + lane];
    const float brow = b[row];
    const float wo   = WoT[row * O_ + lane];

    // Preamble: x(-1) = 0, u(0) staged.
    #pragma unroll
    for (int k = 0; k < SPT; ++k) x_lds[0][tid + k * NTHR] = 0.f;
    if (tid < D_) u_lds[0][tid] = inputs[tid];
    __syncthreads();

    float xo = 0.f;   // x_{t-1}[row], carried in-register (leak term)

    for (int t = 0; t < T_; ++t) {
        const int pt = t & 1;

        // Sparse gather from LDS + input fold + butterfly reduce.
        float acc = 0.f;
        #pragma unroll
        for (int j = 0; j < GRP; ++j) acc += vv[j] * x_lds[pt][cc[j]];
        acc += win * u_lds[pt][lane];
        #pragma unroll
        for (int off = 32; off; off >>= 1) acc += __shfl_xor(acc, off);
        float xn = (1.f - LEAK_) * xo + LEAK_ * tanhf(acc + brow);
        xo = xn;

        // Publish {xn, seq=t+1} atomically — single 8B store, no fence needed.
        if (lane == 0)
            ST64(&xpairs[(size_t)pt * N_ + row], mkpair(xn, (unsigned)(t + 1)));

        // Readout partial for own row; prefetch u(t+1).
        pw_lds[pt][wave][lane] = wo * xn;
        if (t + 1 < T_ && tid < D_) u_lds[pt ^ 1][tid] = inputs[(t + 1) * D_ + tid];

        // Poll x(t) pairs (4 slots/thread) and stage into x_lds[pt^1].
        {
            const u64* xp = xpairs + (size_t)pt * N_;
            const unsigned tgt = (unsigned)(t + 1);
            u64 v[SPT];
            #pragma unroll
            for (int k = 0; k < SPT; ++k) v[k] = LD64(&xp[tid + k * NTHR]);
            while (true) {
                int stale = 0;
                #pragma unroll
                for (int k = 0; k < SPT; ++k)
                    if (pseq(v[k]) != tgt) { v[k] = LD64(&xp[tid + k * NTHR]); stale = 1; }
                if (__ballot(stale) == 0ull) break;
            }
            #pragma unroll
            for (int k = 0; k < SPT; ++k)
                x_lds[pt ^ 1][tid + k * NTHR] = pval(v[k]);
        }
        __syncthreads();   // the ONLY sync per step

        // Post-sync roles (off the inter-block critical path).
        if (wave == 1) {
            // Block partial of y_t: sum 16 per-wave rows, publish with seq.
            float s = 0.f;
            #pragma unroll
            for (int w = 0; w < NWAVE; ++w) s += pw_lds[pt][w][lane];
            ST64(&ppairs[(size_t)(t & (PDEPTH - 1)) * (NBLK * O_) + bid * O_ + lane],
                 mkpair(s, (unsigned)(t + 1)));
        } else if (wave == 2 && t >= 2 && bid < O_) {
            // y(t-2): gather 256 block-partials for output o = bid.
            const u64* pp = ppairs + (size_t)((t - 2) & (PDEPTH - 1)) * (NBLK * O_);
            const unsigned tgt = (unsigned)(t - 1);
            u64 v0 = LD64(&pp[lane * O_ + bid]);
            u64 v1 = LD64(&pp[(lane + 64) * O_ + bid]);
            u64 v2 = LD64(&pp[(lane + 128) * O_ + bid]);
            u64 v3 = LD64(&pp[(lane + 192) * O_ + bid]);
            while (true) {
                int stale = 0;
                if (pseq(v0) != tgt) { v0 = LD64(&pp[lane * O_ + bid]); stale = 1; }
                if (pseq(v1) != tgt) { v1 = LD64(&pp[(lane + 64) * O_ + bid]); stale = 1; }
                if (pseq(v2) != tgt) { v2 = LD64(&pp[(lane + 128) * O_ + bid]); stale = 1; }
                if (pseq(v3) != tgt) { v3 = LD64(&pp[(lane + 192) * O_ + bid]); stale = 1; }
                if (__ballot(stale) == 0ull) break;
            }
            float s = pval(v0) + pval(v1) + pval(v2) + pval(v3);
            #pragma unroll
            for (int off = 32; off; off >>= 1) s += __shfl_xor(s, off);
            if (lane == 0) y[(t - 2) * O_ + bid] = s + bo[bid];
        }
    }

    // Drain y(T-2), y(T-1).
    if (wave == 2 && bid < O_) {
        for (int tt = T_ - 2; tt < T_; ++tt) {
            const u64* pp = ppairs + (size_t)(tt & (PDEPTH - 1)) * (NBLK * O_);
            const unsigned tgt = (unsigned)(tt + 1);
            u64 v0 = LD64(&pp[lane * O_ + bid]);
            u64 v1 = LD64(&pp[(lane + 64) * O_ + bid]);
            u64 v2 = LD64(&pp[(lane + 128) * O_ + bid]);
            u64 v3 = LD64(&pp[(lane + 192) * O_ + bid]);
            while (true) {
                int stale = 0;
                if (pseq(v0) != tgt) { v0 = LD64(&pp[lane * O_ + bid]); stale = 1; }
                if (pseq(v1) != tgt) { v1 = LD64(&pp[(lane + 64) * O_ + bid]); stale = 1; }
                if (pseq(v2) != tgt) { v2 = LD64(&pp[(lane + 128) * O_ + bid]); stale = 1; }
                if (pseq(v3) != tgt) { v3 = LD64(&pp[(lane + 192) * O_ + bid]); stale = 1; }
                if (__ballot(stale) == 0ull) break;
            }
            float s = pval(v0) + pval(v1) + pval(v2) + pval(v3);
            #pragma unroll
            for (int off = 32; off; off >>= 1) s += __shfl_xor(s, off);
            if (lane == 0) y[tt * O_ + bid] = s + bo[bid];
        }
    }
}

extern "C" void kernel_launch(void* const* d_in, const int* in_sizes, int n_in,
                              void* d_out, int out_size, void* d_ws, size_t ws_size,
                              hipStream_t stream) {
    const float* inputs = (const float*)d_in[0];
    const float* W      = (const float*)d_in[1];
    const float* W_in   = (const float*)d_in[2];
    const float* b      = (const float*)d_in[3];
    const float* W_out  = (const float*)d_in[4];
    float* y  = (float*)d_out;

    // Workspace:
    //   xpairs: 2 * N u64         (64 KB)   {x, seq} pairs, ping-pong
    //   ppairs: PDEPTH*NBLK*O u64 (1 MB)    {partial, seq} ring
    //   floats: WoT[N*O] | bo[O] | vals[N*KELL] ; then u16 cols[N*KELL]
    u64* xpairs = (u64*)d_ws;
    u64* ppairs = xpairs + 2 * N_;
    float* WoT  = (float*)(ppairs + (size_t)PDEPTH * NBLK * O_);
    float* bo   = WoT + N_ * O_;
    float* vals = bo + O_;
    unsigned short* cols = (unsigned short*)(vals + (size_t)N_ * KELL);

    // Zero all seq words (xpairs + ppairs) every call -> replay-deterministic.
    size_t seq_bytes = (2 * N_ + (size_t)PDEPTH * NBLK * O_) * sizeof(u64);
    hipMemsetAsync(d_ws, 0, seq_bytes, stream);

    hipLaunchKernelGGL(esn_prep, dim3((N_ * O_ + 255) / 256), dim3(256),
                       0, stream, W_out, WoT, bo);
    hipLaunchKernelGGL(esn_sparsify, dim3(N_), dim3(64),
                       0, stream, W, cols, vals);

    hipLaunchKernelGGL(esn_main, dim3(NBLK), dim3(NTHR), 0, stream,
                       inputs, cols, vals, W_in, b, WoT, bo, y,
                       xpairs, ppairs);
}

// Round 16
// 13611.636 us; speedup vs baseline: 1.7525x; 1.0112x over previous
//
#include <hip/hip_runtime.h>

constexpr int N_ = 4096;
constexpr int D_ = 64;
constexpr int O_ = 64;
constexpr int T_ = 4096;
constexpr float LEAK_ = 0.8f;
constexpr int NBLK = 256;        // 1 block/CU, full machine; all co-resident
constexpr int NTHR = 1024;       // 16 waves
constexpr int NWAVE = 16;
constexpr int RPB = N_ / NBLK;   // 16 rows per block, ONE row per wave
constexpr int KELL = 512;        // ELL slots/row (max nnz ~485, 5-sigma margin)
constexpr int GRP = KELL / 64;   // 8 gather groups
constexpr int PDEPTH = 8;        // y-partials ring depth (skew-proof)
constexpr int SPT = N_ / NTHR;   // 4 x-slots per thread

typedef unsigned long long u64;
#define LD64(p)   __hip_atomic_load((const u64*)(p), __ATOMIC_RELAXED, __HIP_MEMORY_SCOPE_AGENT)
#define ST64(p,v) __hip_atomic_store((u64*)(p), (v), __ATOMIC_RELAXED, __HIP_MEMORY_SCOPE_AGENT)

__device__ __forceinline__ u64 mkpair(float x, unsigned seq) {
    return ((u64)seq << 32) | (u64)__float_as_uint(x);
}
__device__ __forceinline__ unsigned pseq(u64 v) { return (unsigned)(v >> 32); }
__device__ __forceinline__ float pval(u64 v) { return __uint_as_float((unsigned)v); }

// Prep A: transpose W_out weight part -> WoT[row][o], extract bias col bo.
__global__ void esn_prep(const float* __restrict__ W_out,
                         float* __restrict__ WoT, float* __restrict__ bo) {
    int idx = blockIdx.x * blockDim.x + threadIdx.x;
    if (idx < N_ * O_) {
        int row = idx / O_;
        int o = idx - row * O_;
        WoT[idx] = W_out[o * (N_ + 1) + row];
    }
    if (idx < O_) bo[idx] = W_out[idx * (N_ + 1) + N_];
}

// Prep B: dense W -> ELL with BANK-BALANCED slot assignment (bank = col & 31
// round-robined across the 8 slot-groups -> ~2-3-way conflicts, mostly free).
__global__ __launch_bounds__(64) void esn_sparsify(
    const float* __restrict__ W,
    unsigned short* __restrict__ cols, float* __restrict__ vals) {
    const int row = blockIdx.x;
    const int lane = threadIdx.x;
    __shared__ unsigned short nnz_c[KELL];
    __shared__ float nnz_w[KELL];
    __shared__ short slot_nnz[KELL];
    for (int s = lane; s < KELL; s += 64) slot_nnz[s] = -1;

    const float* Wr = W + (size_t)row * N_;
    const unsigned long long ltmask = (1ull << lane) - 1ull;
    int cnt = 0;
    for (int c0 = 0; c0 < N_; c0 += 64) {
        float w = Wr[c0 + lane];
        unsigned long long m = __ballot(w != 0.0f);
        if (w != 0.0f) {
            int pos = cnt + __popcll(m & ltmask);
            if (pos < KELL) { nnz_c[pos] = (unsigned short)(c0 + lane); nnz_w[pos] = w; }
        }
        cnt += __popcll(m);
    }
    if (cnt > KELL) cnt = KELL;
    __syncthreads();

    if (lane == 0) {
        unsigned char fill[GRP];
        unsigned char nxt[32];
        for (int g = 0; g < GRP; ++g) fill[g] = 0;
        for (int bnk = 0; bnk < 32; ++bnk) nxt[bnk] = 0;
        for (int i = 0; i < cnt; ++i) {
            int bnk = nnz_c[i] & 31;
            int g = nxt[bnk];
            int tries = 0;
            while (fill[g] >= 64 && tries < GRP) { g = (g + 1) % GRP; ++tries; }
            slot_nnz[g * 64 + fill[g]] = (short)i;
            fill[g]++;
            nxt[bnk] = (unsigned char)((g + 1) % GRP);
        }
    }
    __syncthreads();

    unsigned short* crow = cols + (size_t)row * KELL;
    float* vrow = vals + (size_t)row * KELL;
    for (int s = lane; s < KELL; s += 64) {
        int i = slot_nnz[s];
        crow[s] = (i >= 0) ? nnz_c[i] : 0;
        vrow[s] = (i >= 0) ? nnz_w[i] : 0.0f;
    }
}

__global__ __launch_bounds__(NTHR) void esn_main(
    const float* __restrict__ inputs,
    const unsigned short* __restrict__ cols, const float* __restrict__ vals,
    const float* __restrict__ W_in, const float* __restrict__ b,
    const float* __restrict__ WoT, const float* __restrict__ bo,
    float* __restrict__ y, u64* __restrict__ xpairs, u64* __restrict__ ppairs)
{
    __shared__ float x_lds[2][N_];          // 32 KB, double-buffered
    __shared__ float u_lds[2][D_];
    __shared__ float pw_lds[2][NWAVE][O_];  // 8 KB
    const int tid = threadIdx.x;
    const int bid = blockIdx.x;
    const int wave = tid >> 6;
    const int lane = tid & 63;
    const int row = bid * RPB + wave;       // this wave's row, for ALL 4096 steps

    // Hoist row-constant weights into registers (zero weight traffic in loop).
    unsigned short cc[GRP];
    float vv[GRP];
    #pragma unroll
    for (int j = 0; j < GRP; ++j) {
        cc[j] = cols[(size_t)row * KELL + 64 * j + lane];
        vv[j] = vals[(size_t)row * KELL + 64 * j + lane];
    }
    const float win  = W_in[row * D_ + lane];
    const float brow = b[row];
    const float wo   = WoT[row * O_ + lane];

    // Preamble: x(-1) = 0, u(0) staged.
    #pragma unroll
    for (int k = 0; k < SPT; ++k) x_lds[0][tid + k * NTHR] = 0.f;
    if (tid < D_) u_lds[0][tid] = inputs[tid];
    __syncthreads();

    float xo = 0.f;   // x_{t-1}[row], carried in-register (leak term)

    for (int t = 0; t < T_; ++t) {
        const int pt = t & 1;

        // Sparse gather from LDS + input fold + butterfly reduce.
        float acc = 0.f;
        #pragma unroll
        for (int j = 0; j < GRP; ++j) acc += vv[j] * x_lds[pt][cc[j]];
        acc += win * u_lds[pt][lane];
        #pragma unroll
        for (int off = 32; off; off >>= 1) acc += __shfl_xor(acc, off);
        float xn = (1.f - LEAK_) * xo + LEAK_ * tanhf(acc + brow);
        xo = xn;

        // Publish {xn, seq=t+1} atomically — single 8B store, no fence needed.
        if (lane == 0)
            ST64(&xpairs[(size_t)pt * N_ + row], mkpair(xn, (unsigned)(t + 1)));

        // Readout partial for own row; prefetch u(t+1).
        pw_lds[pt][wave][lane] = wo * xn;
        if (t + 1 < T_ && tid < D_) u_lds[pt ^ 1][tid] = inputs[(t + 1) * D_ + tid];

        // Poll x(t) pairs (4 slots/thread) and stage into x_lds[pt^1].
        {
            const u64* xp = xpairs + (size_t)pt * N_;
            const unsigned tgt = (unsigned)(t + 1);
            u64 v[SPT];
            #pragma unroll
            for (int k = 0; k < SPT; ++k) v[k] = LD64(&xp[tid + k * NTHR]);
            while (true) {
                int stale = 0;
                #pragma unroll
                for (int k = 0; k < SPT; ++k)
                    if (pseq(v[k]) != tgt) { v[k] = LD64(&xp[tid + k * NTHR]); stale = 1; }
                if (__ballot(stale) == 0ull) break;
            }
            #pragma unroll
            for (int k = 0; k < SPT; ++k)
                x_lds[pt ^ 1][tid + k * NTHR] = pval(v[k]);
        }
        __syncthreads();   // the ONLY sync per step

        // Post-sync roles (off the inter-block critical path).
        if (wave == 1) {
            // Block partial of y_t: sum 16 per-wave rows, publish with seq.
            float s = 0.f;
            #pragma unroll
            for (int w = 0; w < NWAVE; ++w) s += pw_lds[pt][w][lane];
            ST64(&ppairs[(size_t)(t & (PDEPTH - 1)) * (NBLK * O_) + bid * O_ + lane],
                 mkpair(s, (unsigned)(t + 1)));
        } else if (wave == 2 && t >= 2 && bid < O_) {
            // y(t-2): gather 256 block-partials for output o = bid.
            const u64* pp = ppairs + (size_t)((t - 2) & (PDEPTH - 1)) * (NBLK * O_);
            const unsigned tgt = (unsigned)(t - 1);
            u64 v0 = LD64(&pp[lane * O_ + bid]);
            u64 v1 = LD64(&pp[(lane + 64) * O_ + bid]);
            u64 v2 = LD64(&pp[(lane + 128) * O_ + bid]);
            u64 v3 = LD64(&pp[(lane + 192) * O_ + bid]);
            while (true) {
                int stale = 0;
                if (pseq(v0) != tgt) { v0 = LD64(&pp[lane * O_ + bid]); stale = 1; }
                if (pseq(v1) != tgt) { v1 = LD64(&pp[(lane + 64) * O_ + bid]); stale = 1; }
                if (pseq(v2) != tgt) { v2 = LD64(&pp[(lane + 128) * O_ + bid]); stale = 1; }
                if (pseq(v3) != tgt) { v3 = LD64(&pp[(lane + 192) * O_ + bid]); stale = 1; }
                if (__ballot(stale) == 0ull) break;
            }
            float s = pval(v0) + pval(v1) + pval(v2) + pval(v3);
            #pragma unroll
            for (int off = 32; off; off >>= 1) s += __shfl_xor(s, off);
            if (lane == 0) y[(t - 2) * O_ + bid] = s + bo[bid];
        }
    }

    // Drain y(T-2), y(T-1).
    if (wave == 2 && bid < O_) {
        for (int tt = T_ - 2; tt < T_; ++tt) {
            const u64* pp = ppairs + (size_t)(tt & (PDEPTH - 1)) * (NBLK * O_);
            const unsigned tgt = (unsigned)(tt + 1);
            u64 v0 = LD64(&pp[lane * O_ + bid]);
            u64 v1 = LD64(&pp[(lane + 64) * O_ + bid]);
            u64 v2 = LD64(&pp[(lane + 128) * O_ + bid]);
            u64 v3 = LD64(&pp[(lane + 192) * O_ + bid]);
            while (true) {
                int stale = 0;
                if (pseq(v0) != tgt) { v0 = LD64(&pp[lane * O_ + bid]); stale = 1; }
                if (pseq(v1) != tgt) { v1 = LD64(&pp[(lane + 64) * O_ + bid]); stale = 1; }
                if (pseq(v2) != tgt) { v2 = LD64(&pp[(lane + 128) * O_ + bid]); stale = 1; }
                if (pseq(v3) != tgt) { v3 = LD64(&pp[(lane + 192) * O_ + bid]); stale = 1; }
                if (__ballot(stale) == 0ull) break;
            }
            float s = pval(v0) + pval(v1) + pval(v2) + pval(v3);
            #pragma unroll
            for (int off = 32; off; off >>= 1) s += __shfl_xor(s, off);
            if (lane == 0) y[tt * O_ + bid] = s + bo[bid];
        }
    }
}

extern "C" void kernel_launch(void* const* d_in, const int* in_sizes, int n_in,
                              void* d_out, int out_size, void* d_ws, size_t ws_size,
                              hipStream_t stream) {
    const float* inputs = (const float*)d_in[0];
    const float* W      = (const float*)d_in[1];
    const float* W_in   = (const float*)d_in[2];
    const float* b      = (const float*)d_in[3];
    const float* W_out  = (const float*)d_in[4];
    float* y  = (float*)d_out;

    // Workspace:
    //   xpairs: 2 * N u64         (64 KB)   {x, seq} pairs, ping-pong
    //   ppairs: PDEPTH*NBLK*O u64 (1 MB)    {partial, seq} ring
    //   floats: WoT[N*O] | bo[O] | vals[N*KELL] ; then u16 cols[N*KELL]
    u64* xpairs = (u64*)d_ws;
    u64* ppairs = xpairs + 2 * N_;
    float* WoT  = (float*)(ppairs + (size_t)PDEPTH * NBLK * O_);
    float* bo   = WoT + N_ * O_;
    float* vals = bo + O_;
    unsigned short* cols = (unsigned short*)(vals + (size_t)N_ * KELL);

    // Zero all seq words (xpairs + ppairs) every call -> replay-deterministic.
    size_t seq_bytes = (2 * N_ + (size_t)PDEPTH * NBLK * O_) * sizeof(u64);
    hipMemsetAsync(d_ws, 0, seq_bytes, stream);

    hipLaunchKernelGGL(esn_prep, dim3((N_ * O_ + 255) / 256), dim3(256),
                       0, stream, W_out, WoT, bo);
    hipLaunchKernelGGL(esn_sparsify, dim3(N_), dim3(64),
                       0, stream, W, cols, vals);

    hipLaunchKernelGGL(esn_main, dim3(NBLK), dim3(NTHR), 0, stream,
                       inputs, cols, vals, W_in, b, WoT, bo, y,
                       xpairs, ppairs);
}